// Round 14
// baseline (411.408 us; speedup 1.0000x reference)
//
#include <hip/hip_runtime.h>
#include <hip/hip_bf16.h>

#define B_ 32
#define L_ 4096
#define DIN 16
#define H_ 128
#define N2_ 32
#define NL_ 4
#define CL 64
#define NC 64

// ---- workspace layout (float slots) ----
#define OFF_U   ((size_t)0)                   // u bf16 (u16), [b][h][l]
#define SZ_U    ((size_t)B_*H_*L_/2)
#define OFF_Y   (OFF_U + SZ_U)                // y bf16 (u16), [b][h][l]
#define SZ_Y    ((size_t)B_*H_*L_/2)
#define OFF_K   (OFF_Y + SZ_Y)
#define SZ_K    ((size_t)NL_*H_*64)
#define OFF_CP  (OFF_K + SZ_K)
#define SZ_CP   ((size_t)NL_*H_*64)
#define OFF_W64 (OFF_CP + SZ_CP)
#define SZ_W64  ((size_t)NL_*H_*64)
#define OFF_W5  (OFF_W64 + SZ_W64)            // w^512 [lh][n][2]
#define SZ_W5   ((size_t)NL_*H_*64)
#define OFF_DTA (OFF_W5 + SZ_W5)              // (dre,dim,wre,wim) per (lh,n)
#define SZ_DTA  ((size_t)NL_*H_*N2_*4)
#define OFF_PL  (OFF_DTA + SZ_DTA)
#define SZ_PL   ((size_t)B_*H_)
#define OFF_WB  (OFF_PL + SZ_PL)
#define SZ_WB   ((size_t)NL_*256*128/2)
// frag tables: per (lh): 8192 u16 = 4096 float slots. layout: (k>>3)*1024 + col*16 + (k&7), +8 = lo
#define OFF_T1F (OFF_WB + SZ_WB)
#define SZ_TF   ((size_t)NL_*H_*4096)
#define OFF_TKF (OFF_T1F + SZ_TF)
#define OFF_T2F (OFF_TKF + SZ_TF)

#define ZP 72   // u16 pitch, z/G LDS
#define EP 68   // f32 pitch, E LDS

typedef __bf16 bf16_t;
typedef bf16_t bf16x8 __attribute__((ext_vector_type(8)));
typedef float f32x4 __attribute__((ext_vector_type(4)));
typedef unsigned short u16x8 __attribute__((ext_vector_type(8)));

#define MFMA(a, b, c) __builtin_amdgcn_mfma_f32_16x16x32_bf16(a, b, c, 0, 0, 0)
#define BCB(v) __builtin_bit_cast(bf16x8, v)

__device__ __forceinline__ unsigned short f2bf(float f) {
    return __builtin_bit_cast(unsigned short, (__bf16)f);   // native RNE cvt
}
__device__ __forceinline__ float bf2f(unsigned short u) {
    return __builtin_bit_cast(float, (unsigned int)u << 16);
}
__device__ __forceinline__ void store_hl(unsigned short* p, int idx, float v) {
    unsigned short hi = f2bf(v);
    p[idx]     = hi;
    p[idx + 8] = f2bf(v - bf2f(hi));
}
// tanh-GELU: max abs err ~3e-4 (invisible under bf16), branchless, HW exp
__device__ __forceinline__ float gelu_f(float a) {
    float uu = a * fmaf(0.0356774081f, a * a, 0.7978845608f);
    float e  = __expf(2.0f * uu);
    float th = 1.0f - 2.0f / (e + 1.0f);
    return 0.5f * a * (1.0f + th);
}
// yt[l][h] XOR swizzle (u16 index); h must be mult of 8 for 16B access
__device__ __forceinline__ int yswz(int l, int h) {
    return (l * 128 + h) ^ ((l & 7) << 3);
}

// ---------------------------------------------------------------------------
// P0a: per (lh,n): C', dtA cache, w, w^64, w^512 (all direct, no serial chain)
// ---------------------------------------------------------------------------
__global__ __launch_bounds__(256) void prep_params(const float* log_dt, const float* log_A_real,
                                                   const float* A_imag, const float* C_re,
                                                   const float* C_im, float* ws) {
    int idx = blockIdx.x * 256 + threadIdx.x;        // (lh,n)
    if (idx >= NL_ * H_ * N2_) return;
    int n  = idx & 31;
    int lh = idx >> 5;

    float dt  = expf(log_dt[lh]);
    float Are = -expf(log_A_real[idx]);
    float Aim = A_imag[idx];
    float dre = Are * dt, dim = Aim * dt;
    float er  = expf(dre);
    float sw, cw; sincosf(dim, &sw, &cw);
    float wre = er * cw, wim = er * sw;
    float nre = wre - 1.0f, nim = wim;
    float den = Are * Are + Aim * Aim;
    float qre = (nre * Are + nim * Aim) / den;
    float qim = (nim * Are - nre * Aim) / den;
    float cre = C_re[idx], cim = C_im[idx];

    float* cp  = ws + OFF_CP  + (size_t)lh * 64;
    float* w64 = ws + OFF_W64 + (size_t)lh * 64;
    float* w5  = ws + OFF_W5  + (size_t)lh * 64;
    cp[2 * n]     = cre * qre - cim * qim;
    cp[2 * n + 1] = cre * qim + cim * qre;
    *((float4*)(ws + OFF_DTA) + (size_t)lh * 32 + n) = make_float4(dre, dim, wre, wim);

    float e64 = expf(64.0f * dre);
    float s64, c64; sincosf(64.0f * dim, &s64, &c64);
    float ar = e64 * c64, ai = e64 * s64;
    w64[2 * n] = ar; w64[2 * n + 1] = ai;
    #pragma unroll
    for (int q = 0; q < 3; ++q) {
        float nr = ar * ar - ai * ai;
        float ni = 2.0f * ar * ai;
        ar = nr; ai = ni;
    }
    w5[2 * n] = ar; w5[2 * n + 1] = ai;
}

// ---------------------------------------------------------------------------
// P0b: per (lh,e,n): w^e direct -> T1F frag; w^{e+1} -> T2F frag
// ---------------------------------------------------------------------------
__global__ __launch_bounds__(256) void prep_pow(float* ws) {
    int idx = blockIdx.x * 256 + threadIdx.x;        // lh*2048 + e*32 + n
    int n  = idx & 31;
    int e  = (idx >> 5) & 63;
    int lh = idx >> 11;
    float4 dw = *((const float4*)(ws + OFF_DTA) + (size_t)lh * 32 + n);
    float ew = expf((float)e * dw.x);
    float sn, cs; sincosf((float)e * dw.y, &sn, &cs);
    float pr = ew * cs, pi = ew * sn;

    unsigned short* t1f = (unsigned short*)(ws + OFF_T1F) + (size_t)lh * 8192;
    unsigned short* t2f = (unsigned short*)(ws + OFF_T2F) + (size_t)lh * 8192;
    int k1 = 63 - e;                                 // T1F[k1][np] = w^e
    store_hl(t1f, (k1 >> 3) * 1024 + (2 * n) * 16 + (k1 & 7), pr);
    store_hl(t1f, (k1 >> 3) * 1024 + (2 * n + 1) * 16 + (k1 & 7), pi);
    float qr = pr * dw.z - pi * dw.w;                // w^{e+1}
    float qi = pr * dw.w + pi * dw.z;
    store_hl(t2f, ((2 * n) >> 3) * 1024 + e * 16 + ((2 * n) & 7), qr);
    store_hl(t2f, ((2 * n + 1) >> 3) * 1024 + e * 16 + ((2 * n + 1) & 7), qi);
}

// ---------------------------------------------------------------------------
// P0c: k[lh][s] = 2*Re( sum_n C'_n w_n^s ); w^s recomputed (round-10 order)
// ---------------------------------------------------------------------------
__global__ __launch_bounds__(256) void compute_k(float* ws) {
    int idx = blockIdx.x * 256 + threadIdx.x;        // (lh, s)
    if (idx >= NL_ * H_ * 64) return;
    int s  = idx & 63;
    int lh = idx >> 6;
    const float* cp = ws + OFF_CP + (size_t)lh * 64;
    const float4* dta = (const float4*)(ws + OFF_DTA) + (size_t)lh * 32;
    float acc = 0.0f;
    #pragma unroll 8
    for (int n = 0; n < 32; ++n) {
        float4 dw = dta[n];
        float ew = expf((float)s * dw.x);
        float sn, cs; sincosf((float)s * dw.y, &sn, &cs);
        acc += cp[2 * n] * (ew * cs) - cp[2 * n + 1] * (ew * sn);
    }
    ws[OFF_K + (size_t)lh * 64 + s] = 2.0f * acc;
}

// ---------------------------------------------------------------------------
// P0d: Toeplitz frag table TKF[s][tau] = (tau>=s) ? k[tau-s] : 0  (parallel)
// ---------------------------------------------------------------------------
__global__ __launch_bounds__(256) void prep_tkf(float* ws) {
    int idx = blockIdx.x * 256 + threadIdx.x;        // lh*4096 + s*64 + tau
    int tau = idx & 63;
    int s   = (idx >> 6) & 63;
    int lh  = idx >> 12;
    float v = (tau >= s) ? ws[OFF_K + (size_t)lh * 64 + (tau - s)] : 0.0f;
    unsigned short* dst = (unsigned short*)(ws + OFF_TKF) + (size_t)lh * 8192;
    store_hl(dst, (s >> 3) * 1024 + (s & 7) + tau * 16, v);
}

// ---------------------------------------------------------------------------
// P0e: conv_w -> bf16
// ---------------------------------------------------------------------------
__global__ __launch_bounds__(256) void prep_wbf(const float* conv_w, float* ws) {
    int i = blockIdx.x * 256 + threadIdx.x;
    ((unsigned short*)(ws + OFF_WB))[i] = f2bf(conv_w[i]);
}

// ---------------------------------------------------------------------------
// Encoder -> u bf16
// ---------------------------------------------------------------------------
__global__ __launch_bounds__(256) void encoder_kernel(const float* x, const float* enc_w,
                                                      const float* enc_b, float* ws) {
    __shared__ float wlds[H_ * DIN];
    __shared__ float blds[H_];
    int t  = threadIdx.x;
    int b  = blockIdx.x >> 4;
    int l0 = (blockIdx.x & 15) * 256;
    for (int i = t; i < H_ * DIN; i += 256) wlds[i] = enc_w[i];
    if (t < H_) blds[t] = enc_b[t];
    float xr[16];
    const float* xp = x + ((size_t)b * L_ + l0 + t) * DIN;
    #pragma unroll
    for (int d = 0; d < 16; ++d) xr[d] = xp[d];
    __syncthreads();
    unsigned short* u = (unsigned short*)(ws + OFF_U) + (size_t)b * H_ * L_ + l0 + t;
    for (int h = 0; h < H_; ++h) {
        float acc = blds[h];
        #pragma unroll
        for (int d = 0; d < 16; ++d) acc += xr[d] * wlds[h * 16 + d];
        u[(size_t)h * L_] = f2bf(acc);
    }
}

// ---------------------------------------------------------------------------
// S4D via bf16 MFMA (T tables hi/lo corrected; z/G pure bf16).
// One block per (b,h). Parallel 3-level cross-chunk scan (round-10 verbatim).
// ---------------------------------------------------------------------------
__global__ __launch_bounds__(256) void s4d_mfma(const float* Dp, float* ws, int layer) {
    __shared__ unsigned short zsh[64 * ZP];   // z, then G (bf16)
    __shared__ float eg[64 * EP];             // E (f32)
    __shared__ float tex[8][64];              // octave totals (complex packed)
    __shared__ float bex[8][64];              // exclusive octave bases

    int t  = threadIdx.x;
    int b  = blockIdx.x >> 7;
    int h  = blockIdx.x & 127;
    int lh = layer * H_ + h;
    int w  = t >> 6;
    int l  = t & 63;
    int lr = l & 15;
    int lg = l >> 4;

    const unsigned short* ug = (const unsigned short*)(ws + OFF_U) + ((size_t)b * H_ + h) * L_;

    // stage z: straight bf16 copy (16 elements per thread)
    {
        int base = t * 16;
        int c = base >> 6, s0 = base & 63;
        *(u16x8*)&zsh[c * ZP + s0]     = *(const u16x8*)&ug[base];
        *(u16x8*)&zsh[c * ZP + s0 + 8] = *(const u16x8*)&ug[base + 8];
    }

    // preload B-frags (global, L2-hot): T1F + TKF, kblk 0/1
    const unsigned short* t1f = (const unsigned short*)(ws + OFF_T1F) + (size_t)lh * 8192;
    const unsigned short* tkf = (const unsigned short*)(ws + OFF_TKF) + (size_t)lh * 8192;
    const unsigned short* t2f = (const unsigned short*)(ws + OFF_T2F) + (size_t)lh * 8192;
    int bo = lg * 1024 + (w * 16 + lr) * 16;
    bf16x8 T1h0 = BCB(*(const u16x8*)&t1f[bo]);
    bf16x8 T1l0 = BCB(*(const u16x8*)&t1f[bo + 8]);
    bf16x8 T1h1 = BCB(*(const u16x8*)&t1f[bo + 4096]);
    bf16x8 T1l1 = BCB(*(const u16x8*)&t1f[bo + 4096 + 8]);
    bf16x8 TKh0 = BCB(*(const u16x8*)&tkf[bo]);
    bf16x8 TKl0 = BCB(*(const u16x8*)&tkf[bo + 8]);
    bf16x8 TKh1 = BCB(*(const u16x8*)&tkf[bo + 4096]);
    bf16x8 TKl1 = BCB(*(const u16x8*)&tkf[bo + 4096 + 8]);

    f32x4 accE[4], accC[4];
    #pragma unroll
    for (int ct = 0; ct < 4; ++ct) { accE[ct] = (f32x4)0.0f; accC[ct] = (f32x4)0.0f; }

    __syncthreads();

    // ---- Pass A: E = z x (T1h+T1l) ; Yconv = z x (TKh+TKl)
    #pragma unroll
    for (int ct = 0; ct < 4; ++ct) {
        int ar = (ct * 16 + lr) * ZP;
        bf16x8 ah0 = BCB(*(const u16x8*)&zsh[ar + lg * 8]);
        bf16x8 ah1 = BCB(*(const u16x8*)&zsh[ar + 32 + lg * 8]);
        accE[ct] = MFMA(ah0, T1h0, accE[ct]);
        accE[ct] = MFMA(ah0, T1l0, accE[ct]);
        accE[ct] = MFMA(ah1, T1h1, accE[ct]);
        accE[ct] = MFMA(ah1, T1l1, accE[ct]);
        accC[ct] = MFMA(ah0, TKh0, accC[ct]);
        accC[ct] = MFMA(ah0, TKl0, accC[ct]);
        accC[ct] = MFMA(ah1, TKh1, accC[ct]);
        accC[ct] = MFMA(ah1, TKl1, accC[ct]);
    }
    // write E (D-frag: row=(lg*4+r), col=lr)
    #pragma unroll
    for (int ct = 0; ct < 4; ++ct)
        #pragma unroll
        for (int r = 0; r < 4; ++r)
            eg[(ct * 16 + lg * 4 + r) * EP + w * 16 + lr] = accE[ct][r];

    // preload T2F frags; pre-extract epilogue z (zsh reused for G after)
    bf16x8 T2h0 = BCB(*(const u16x8*)&t2f[bo]);
    bf16x8 T2l0 = BCB(*(const u16x8*)&t2f[bo + 8]);
    bf16x8 T2h1 = BCB(*(const u16x8*)&t2f[bo + 4096]);
    bf16x8 T2l1 = BCB(*(const u16x8*)&t2f[bo + 4096 + 8]);
    float zep[16];
    #pragma unroll
    for (int ct = 0; ct < 4; ++ct)
        #pragma unroll
        for (int r = 0; r < 4; ++r) {
            int c = ct * 16 + lg * 4 + r, tau = w * 16 + lr;
            zep[ct * 4 + r] = bf2f(zsh[c * ZP + tau]);
        }
    __syncthreads();

    // ---- Parallel scan: thread = (n = t&31, oct = t>>5); 8 chunks each
    {
        int n   = t & 31;
        int oct = t >> 5;
        const float* cp   = ws + OFF_CP  + (size_t)lh * 64;
        const float* w64p = ws + OFF_W64 + (size_t)lh * 64;
        const float* w5p  = ws + OFF_W5  + (size_t)lh * 64;
        float cre = cp[2 * n], cim = cp[2 * n + 1];
        float wr  = w64p[2 * n], wi = w64p[2 * n + 1];
        float2 e[8];
        float sre = 0.f, sim = 0.f;
        #pragma unroll
        for (int j = 0; j < 8; ++j) {                 // local octave scan
            e[j] = *(const float2*)&eg[(8 * oct + j) * EP + 2 * n];
            float nr = fmaf(wr, sre, fmaf(-wi, sim, e[j].x));
            float ni = fmaf(wr, sim, fmaf(wi, sre, e[j].y));
            sre = nr; sim = ni;
        }
        *(float2*)&tex[oct][2 * n] = make_float2(sre, sim);
        __syncthreads();
        if (t < 32) {                                 // exclusive base scan over octaves
            float Wr = w5p[2 * n], Wi = w5p[2 * n + 1];
            float br = 0.f, bi = 0.f;
            #pragma unroll
            for (int o = 0; o < 8; ++o) {
                *(float2*)&bex[o][2 * n] = make_float2(br, bi);
                float2 T = *(const float2*)&tex[o][2 * n];
                float nr = fmaf(Wr, br, fmaf(-Wi, bi, T.x));
                float ni = fmaf(Wr, bi, fmaf(Wi, br, T.y));
                br = nr; bi = ni;
            }
        }
        __syncthreads();
        float2 Sb = *(const float2*)&bex[oct][2 * n];
        sre = Sb.x; sim = Sb.y;
        #pragma unroll
        for (int j = 0; j < 8; ++j) {                 // replay: emit G bf16 (packed u32)
            int c = 8 * oct + j;
            float gre = 2.0f * (cre * sre - cim * sim);
            float gim = -2.0f * (cre * sim + cim * sre);
            unsigned int pk = (unsigned int)f2bf(gre) | ((unsigned int)f2bf(gim) << 16);
            *(unsigned int*)&zsh[c * ZP + 2 * n] = pk;
            float nr = fmaf(wr, sre, fmaf(-wi, sim, e[j].x));
            float ni = fmaf(wr, sim, fmaf(wi, sre, e[j].y));
            sre = nr; sim = ni;
        }
    }
    float Dh = Dp[lh];
    __syncthreads();

    // ---- Pass B: Y += G x (T2h+T2l)
    #pragma unroll
    for (int ct = 0; ct < 4; ++ct) {
        int ar = (ct * 16 + lr) * ZP;
        bf16x8 gh0 = BCB(*(const u16x8*)&zsh[ar + lg * 8]);
        bf16x8 gh1 = BCB(*(const u16x8*)&zsh[ar + 32 + lg * 8]);
        accC[ct] = MFMA(gh0, T2h0, accC[ct]);
        accC[ct] = MFMA(gh0, T2l0, accC[ct]);
        accC[ct] = MFMA(gh1, T2h1, accC[ct]);
        accC[ct] = MFMA(gh1, T2l1, accC[ct]);
    }

    // ---- epilogue: + D*z, tanh-GELU, store y bf16 (block-exclusive row)
    unsigned short* yb = (unsigned short*)(ws + OFF_Y) + ((size_t)b * H_ + h) * L_;
    #pragma unroll
    for (int ct = 0; ct < 4; ++ct)
        #pragma unroll
        for (int r = 0; r < 4; ++r) {
            float acc = fmaf(Dh, zep[ct * 4 + r], accC[ct][r]);
            yb[(ct * 16 + lg * 4 + r) * 64 + w * 16 + lr] = f2bf(gelu_f(acc));
        }
}

// ---------------------------------------------------------------------------
// Channel mix via bf16 MFMA + GLU + residual(bf16) + LN -> u bf16.
// Two 64-l tiles per block, pipelined: tile1 global->reg loads issued under
// tile0 epilogue; LDS rewrite separated by existing barriers.
// If last!=0, also write emb output f32 [b][l][h] from registers.
// ---------------------------------------------------------------------------
__global__ __launch_bounds__(256) void conv_glu_ln_mfma(const float* conv_b, const float* ln_w,
                                                        const float* ln_b, float* ws, float* outp,
                                                        int layer, int last) {
    __shared__ unsigned short yt[64 * 128];   // [l][h], swizzled
    __shared__ float wsum[4][64];
    __shared__ float wsq[4][64];

    int t    = threadIdx.x;
    int b    = blockIdx.x >> 5;
    int lbp  = blockIdx.x & 31;               // tile pair: l in [lbp*128, lbp*128+128)
    int w    = t >> 6;
    int lam  = t & 63;
    int g4   = lam >> 4;
    int ncol = lam & 15;
    int ll   = t & 63;
    int hbs  = (t >> 6) * 32;                 // staging h-base

    const unsigned short* yg = (const unsigned short*)(ws + OFF_Y) + (size_t)b * H_ * L_;
    const unsigned short* wb = (const unsigned short*)(ws + OFF_WB) + (size_t)layer * 256 * 128;
    unsigned short* ug = (unsigned short*)(ws + OFF_U) + (size_t)b * H_ * L_;
    const float* cb = conv_b + layer * 256;

    // LN params (same channels both tiles)
    float lwv[2][4], lbv[2][4];
    #pragma unroll
    for (int oa = 0; oa < 2; ++oa)
        #pragma unroll
        for (int r = 0; r < 4; ++r) {
            int hh = layer * 128 + w * 32 + oa * 16 + g4 * 4 + r;
            lwv[oa][r] = ln_w[hh]; lbv[oa][r] = ln_b[hh];
        }

    // ---- stage tile 0 (regs -> LDS)
    u16x8 sr[4];
    {
        const unsigned short* ycol = yg + lbp * 128 + ll;
        #pragma unroll
        for (int g = 0; g < 4; ++g) {
            u16x8 tmp;
            #pragma unroll
            for (int i = 0; i < 8; ++i)
                tmp[i] = ycol[(size_t)(hbs + g * 8 + i) * L_];
            sr[g] = tmp;
        }
        #pragma unroll
        for (int g = 0; g < 4; ++g) *(u16x8*)&yt[yswz(ll, hbs + g * 8)] = sr[g];
    }
    __syncthreads();

    #pragma unroll 1
    for (int tile = 0; tile < 2; ++tile) {
        int l0 = lbp * 128 + tile * 64;

        // ---- bias init
        f32x4 dA[2][4], dG[2][4];
        #pragma unroll
        for (int oa = 0; oa < 2; ++oa) {
            int ba = w * 32 + oa * 16 + g4 * 4;
            f32x4 bA, bG;
            #pragma unroll
            for (int r = 0; r < 4; ++r) { bA[r] = cb[ba + r]; bG[r] = cb[128 + ba + r]; }
            #pragma unroll
            for (int nt = 0; nt < 4; ++nt) { dA[oa][nt] = bA; dG[oa][nt] = bG; }
        }

        // ---- K loop: A-frags from global (L2), B-frags via b128 LDS reads
        #pragma unroll
        for (int kt = 0; kt < 4; ++kt) {
            bf16x8 aAk[2], aGk[2];
            #pragma unroll
            for (int oa = 0; oa < 2; ++oa) {
                int oA = w * 32 + oa * 16 + ncol;
                aAk[oa] = BCB(*(const u16x8*)&wb[(size_t)oA * 128 + kt * 32 + g4 * 8]);
                aGk[oa] = BCB(*(const u16x8*)&wb[(size_t)(128 + oA) * 128 + kt * 32 + g4 * 8]);
            }
            #pragma unroll
            for (int nt = 0; nt < 4; ++nt) {
                bf16x8 bfr = BCB(*(const u16x8*)&yt[yswz(nt * 16 + ncol, kt * 32 + g4 * 8)]);
                #pragma unroll
                for (int oa = 0; oa < 2; ++oa) {
                    dA[oa][nt] = MFMA(aAk[oa], bfr, dA[oa][nt]);
                    dG[oa][nt] = MFMA(aGk[oa], bfr, dG[oa][nt]);
                }
            }
        }

        // ---- prefetch tile1 y -> regs (latency hides under epilogue below)
        if (tile == 0) {
            const unsigned short* ycol = yg + lbp * 128 + 64 + ll;
            #pragma unroll
            for (int g = 0; g < 4; ++g) {
                u16x8 tmp;
                #pragma unroll
                for (int i = 0; i < 8; ++i)
                    tmp[i] = ycol[(size_t)(hbs + g * 8 + i) * L_];
                sr[g] = tmp;
            }
        }

        // ---- epilogue: GLU + residual (bf16); LN over 128 channels
        #pragma unroll
        for (int nt = 0; nt < 4; ++nt) {
            int l = l0 + nt * 16 + ncol;
            float s = 0.f, q = 0.f;
            #pragma unroll
            for (int oa = 0; oa < 2; ++oa)
                #pragma unroll
                for (int r = 0; r < 4; ++r) {
                    int h = w * 32 + oa * 16 + g4 * 4 + r;
                    float a = dA[oa][nt][r], g = dG[oa][nt][r];
                    float val = a / (1.0f + __expf(-g)) + bf2f(ug[(size_t)h * L_ + l]);
                    dA[oa][nt][r] = val;
                    s += val; q += val * val;
                }
            s += __shfl_xor(s, 16, 64); q += __shfl_xor(q, 16, 64);
            s += __shfl_xor(s, 32, 64); q += __shfl_xor(q, 32, 64);
            if (g4 == 0) { wsum[w][nt * 16 + ncol] = s; wsq[w][nt * 16 + ncol] = q; }
        }
        __syncthreads();                       // barrier #E: K reads done block-wide

        // tile1 LDS write: safe here (all K reads of tile0 precede #E)
        if (tile == 0) {
            #pragma unroll
            for (int g = 0; g < 4; ++g) *(u16x8*)&yt[yswz(ll, hbs + g * 8)] = sr[g];
        }

        #pragma unroll
        for (int nt = 0; nt < 4; ++nt) {
            int ll2 = nt * 16 + ncol;
            int l   = l0 + ll2;
            float S = wsum[0][ll2] + wsum[1][ll2] + wsum[2][ll2] + wsum[3][ll2];
            float Q = wsq[0][ll2] + wsq[1][ll2] + wsq[2][ll2] + wsq[3][ll2];
            float mu = S * (1.0f / 128.0f);
            float var = Q * (1.0f / 128.0f) - mu * mu;
            float rstd = rsqrtf(var + 1e-5f);
            #pragma unroll
            for (int oa = 0; oa < 2; ++oa) {
                float vv[4];
                #pragma unroll
                for (int r = 0; r < 4; ++r) {
                    int h = w * 32 + oa * 16 + g4 * 4 + r;
                    float v = (dA[oa][nt][r] - mu) * rstd * lwv[oa][r] + lbv[oa][r];
                    vv[r] = v;
                    ug[(size_t)h * L_ + l] = f2bf(v);
                }
                if (last) {
                    *(float4*)&outp[((size_t)(b * L_ + l)) * H_ + w * 32 + oa * 16 + g4 * 4] =
                        make_float4(vv[0], vv[1], vv[2], vv[3]);
                }
            }
        }
        if (tile == 0) __syncthreads();        // barrier #S: yt(t1) + wsum reuse ordering
    }
}

// ---------------------------------------------------------------------------
// Mean-pool over L per (b,h)
// ---------------------------------------------------------------------------
__global__ __launch_bounds__(256) void pool_kernel(float* ws) {
    int bh = blockIdx.x;
    const unsigned short* u = (const unsigned short*)(ws + OFF_U) + (size_t)bh * L_;
    int t = threadIdx.x;
    float s = 0.0f;
    for (int i = t; i < L_; i += 256) s += bf2f(u[i]);
    #pragma unroll
    for (int m = 1; m <= 32; m <<= 1) s += __shfl_xor(s, m, 64);
    __shared__ float part[4];
    if ((t & 63) == 0) part[t >> 6] = s;
    __syncthreads();
    if (t == 0) ws[OFF_PL + bh] = (part[0] + part[1] + part[2] + part[3]) * (1.0f / L_);
}

// ---------------------------------------------------------------------------
// Decoder (f32 out)
// ---------------------------------------------------------------------------
__global__ __launch_bounds__(256) void decode_kernel(const float* dec_w, const float* dec_b,
                                                     const float* ws, float* out) {
    int t = threadIdx.x;
    int b = t >> 3, o = t & 7;
    const float* p = ws + OFF_PL + b * 128;
    float acc = dec_b[o];
    for (int h = 0; h < 128; ++h) acc += p[h] * dec_w[o * 128 + h];
    out[t] = 1.0f / (1.0f + __expf(-acc));
}

// ---------------------------------------------------------------------------
extern "C" void kernel_launch(void* const* d_in, const int* in_sizes, int n_in,
                              void* d_out, int out_size, void* d_ws, size_t ws_size,
                              hipStream_t stream) {
    const float* x          = (const float*)d_in[0];
    const float* enc_w      = (const float*)d_in[2];
    const float* enc_b      = (const float*)d_in[3];
    const float* log_dt     = (const float*)d_in[4];
    const float* log_A_real = (const float*)d_in[5];
    const float* A_imag     = (const float*)d_in[6];
    const float* C_re       = (const float*)d_in[7];
    const float* C_im       = (const float*)d_in[8];
    const float* Dp         = (const float*)d_in[9];
    const float* conv_w     = (const float*)d_in[10];
    const float* conv_b     = (const float*)d_in[11];
    const float* ln_w       = (const float*)d_in[12];
    const float* ln_b       = (const float*)d_in[13];
    const float* dec_w      = (const float*)d_in[14];
    const float* dec_b      = (const float*)d_in[15];
    float* ws = (float*)d_ws;
    float* out = (float*)d_out;

    prep_params<<<(NL_ * H_ * N2_ + 255) / 256, 256, 0, stream>>>(log_dt, log_A_real, A_imag,
                                                                  C_re, C_im, ws);
    prep_pow<<<(NL_ * H_ * N2_ * 64) / 256, 256, 0, stream>>>(ws);
    compute_k<<<(NL_ * H_ * 64 + 255) / 256, 256, 0, stream>>>(ws);
    prep_tkf<<<(NL_ * H_ * 64 * 64) / 256, 256, 0, stream>>>(ws);
    prep_wbf<<<(NL_ * 256 * 128) / 256, 256, 0, stream>>>(conv_w, ws);
    encoder_kernel<<<B_ * (L_ / 256), 256, 0, stream>>>(x, enc_w, enc_b, ws);
    for (int l = 0; l < NL_; ++l) {
        s4d_mfma<<<B_ * H_, 256, 0, stream>>>(Dp, ws, l);
        conv_glu_ln_mfma<<<B_ * 32, 256, 0, stream>>>(conv_b, ln_w, ln_b, ws,
                                                      out + 256, l, l == NL_ - 1);
    }
    pool_kernel<<<B_ * H_, 256, 0, stream>>>(ws);
    decode_kernel<<<1, 256, 0, stream>>>(dec_w, dec_b, ws, out);
}

// Round 16
// 355.306 us; speedup vs baseline: 1.1579x; 1.1579x over previous
//
#include <hip/hip_runtime.h>
#include <hip/hip_bf16.h>

#define B_ 32
#define L_ 4096
#define DIN 16
#define H_ 128
#define N2_ 32
#define NL_ 4
#define CL 64
#define NC 64

// ---- workspace layout (float slots) ----
#define OFF_U   ((size_t)0)                   // u bf16 (u16), [b][h][l]
#define SZ_U    ((size_t)B_*H_*L_/2)
#define OFF_Y   (OFF_U + SZ_U)                // y bf16 (u16), [b][h][l]
#define SZ_Y    ((size_t)B_*H_*L_/2)
#define OFF_K   (OFF_Y + SZ_Y)
#define SZ_K    ((size_t)NL_*H_*64)
#define OFF_CP  (OFF_K + SZ_K)
#define SZ_CP   ((size_t)NL_*H_*64)
#define OFF_W64 (OFF_CP + SZ_CP)
#define SZ_W64  ((size_t)NL_*H_*64)
#define OFF_W5  (OFF_W64 + SZ_W64)            // w^512 [lh][n][2]
#define SZ_W5   ((size_t)NL_*H_*64)
#define OFF_DTA (OFF_W5 + SZ_W5)              // (dre,dim,wre,wim) per (lh,n)
#define SZ_DTA  ((size_t)NL_*H_*N2_*4)
#define OFF_PL  (OFF_DTA + SZ_DTA)
#define SZ_PL   ((size_t)B_*H_)
#define OFF_WB  (OFF_PL + SZ_PL)
#define SZ_WB   ((size_t)NL_*256*128/2)
// frag tables: per (lh): 8192 u16 = 4096 float slots. layout: (k>>3)*1024 + col*16 + (k&7), +8 = lo
#define OFF_T1F (OFF_WB + SZ_WB)
#define SZ_TF   ((size_t)NL_*H_*4096)
#define OFF_TKF (OFF_T1F + SZ_TF)
#define OFF_T2F (OFF_TKF + SZ_TF)

#define ZP 72   // u16 pitch, z/G LDS
#define EP 68   // f32 pitch, E LDS

typedef __bf16 bf16_t;
typedef bf16_t bf16x8 __attribute__((ext_vector_type(8)));
typedef float f32x4 __attribute__((ext_vector_type(4)));
typedef unsigned short u16x8 __attribute__((ext_vector_type(8)));

#define MFMA(a, b, c) __builtin_amdgcn_mfma_f32_16x16x32_bf16(a, b, c, 0, 0, 0)
#define BCB(v) __builtin_bit_cast(bf16x8, v)

__device__ __forceinline__ unsigned short f2bf(float f) {
    return __builtin_bit_cast(unsigned short, (__bf16)f);   // native RNE cvt
}
__device__ __forceinline__ float bf2f(unsigned short u) {
    return __builtin_bit_cast(float, (unsigned int)u << 16);
}
__device__ __forceinline__ void store_hl(unsigned short* p, int idx, float v) {
    unsigned short hi = f2bf(v);
    p[idx]     = hi;
    p[idx + 8] = f2bf(v - bf2f(hi));
}
// tanh-GELU: max abs err ~3e-4 (invisible under bf16), branchless, HW exp
__device__ __forceinline__ float gelu_f(float a) {
    float uu = a * fmaf(0.0356774081f, a * a, 0.7978845608f);
    float e  = __expf(2.0f * uu);
    float th = 1.0f - 2.0f / (e + 1.0f);
    return 0.5f * a * (1.0f + th);
}
// yt[l][h] XOR swizzle (u16 index); h must be mult of 8 for 16B access
__device__ __forceinline__ int yswz(int l, int h) {
    return (l * 128 + h) ^ ((l & 7) << 3);
}

// ---------------------------------------------------------------------------
// P0a: per (lh,n): C', dtA cache, w, w^64, w^512 (all direct, no serial chain)
// ---------------------------------------------------------------------------
__global__ __launch_bounds__(256) void prep_params(const float* log_dt, const float* log_A_real,
                                                   const float* A_imag, const float* C_re,
                                                   const float* C_im, float* ws) {
    int idx = blockIdx.x * 256 + threadIdx.x;        // (lh,n)
    if (idx >= NL_ * H_ * N2_) return;
    int n  = idx & 31;
    int lh = idx >> 5;

    float dt  = expf(log_dt[lh]);
    float Are = -expf(log_A_real[idx]);
    float Aim = A_imag[idx];
    float dre = Are * dt, dim = Aim * dt;
    float er  = expf(dre);
    float sw, cw; sincosf(dim, &sw, &cw);
    float wre = er * cw, wim = er * sw;
    float nre = wre - 1.0f, nim = wim;
    float den = Are * Are + Aim * Aim;
    float qre = (nre * Are + nim * Aim) / den;
    float qim = (nim * Are - nre * Aim) / den;
    float cre = C_re[idx], cim = C_im[idx];

    float* cp  = ws + OFF_CP  + (size_t)lh * 64;
    float* w64 = ws + OFF_W64 + (size_t)lh * 64;
    float* w5  = ws + OFF_W5  + (size_t)lh * 64;
    cp[2 * n]     = cre * qre - cim * qim;
    cp[2 * n + 1] = cre * qim + cim * qre;
    *((float4*)(ws + OFF_DTA) + (size_t)lh * 32 + n) = make_float4(dre, dim, wre, wim);

    float e64 = expf(64.0f * dre);
    float s64, c64; sincosf(64.0f * dim, &s64, &c64);
    float ar = e64 * c64, ai = e64 * s64;
    w64[2 * n] = ar; w64[2 * n + 1] = ai;
    #pragma unroll
    for (int q = 0; q < 3; ++q) {
        float nr = ar * ar - ai * ai;
        float ni = 2.0f * ar * ai;
        ar = nr; ai = ni;
    }
    w5[2 * n] = ar; w5[2 * n + 1] = ai;
}

// ---------------------------------------------------------------------------
// P0b: per (lh,e,n): w^e direct -> T1F frag; w^{e+1} -> T2F frag
// ---------------------------------------------------------------------------
__global__ __launch_bounds__(256) void prep_pow(float* ws) {
    int idx = blockIdx.x * 256 + threadIdx.x;        // lh*2048 + e*32 + n
    int n  = idx & 31;
    int e  = (idx >> 5) & 63;
    int lh = idx >> 11;
    float4 dw = *((const float4*)(ws + OFF_DTA) + (size_t)lh * 32 + n);
    float ew = expf((float)e * dw.x);
    float sn, cs; sincosf((float)e * dw.y, &sn, &cs);
    float pr = ew * cs, pi = ew * sn;

    unsigned short* t1f = (unsigned short*)(ws + OFF_T1F) + (size_t)lh * 8192;
    unsigned short* t2f = (unsigned short*)(ws + OFF_T2F) + (size_t)lh * 8192;
    int k1 = 63 - e;                                 // T1F[k1][np] = w^e
    store_hl(t1f, (k1 >> 3) * 1024 + (2 * n) * 16 + (k1 & 7), pr);
    store_hl(t1f, (k1 >> 3) * 1024 + (2 * n + 1) * 16 + (k1 & 7), pi);
    float qr = pr * dw.z - pi * dw.w;                // w^{e+1}
    float qi = pr * dw.w + pi * dw.z;
    store_hl(t2f, ((2 * n) >> 3) * 1024 + e * 16 + ((2 * n) & 7), qr);
    store_hl(t2f, ((2 * n + 1) >> 3) * 1024 + e * 16 + ((2 * n + 1) & 7), qi);
}

// ---------------------------------------------------------------------------
// P0c: k[lh][s] = 2*Re( sum_n C'_n w_n^s ); w^s recomputed (round-10 order)
// ---------------------------------------------------------------------------
__global__ __launch_bounds__(256) void compute_k(float* ws) {
    int idx = blockIdx.x * 256 + threadIdx.x;        // (lh, s)
    if (idx >= NL_ * H_ * 64) return;
    int s  = idx & 63;
    int lh = idx >> 6;
    const float* cp = ws + OFF_CP + (size_t)lh * 64;
    const float4* dta = (const float4*)(ws + OFF_DTA) + (size_t)lh * 32;
    float acc = 0.0f;
    #pragma unroll 8
    for (int n = 0; n < 32; ++n) {
        float4 dw = dta[n];
        float ew = expf((float)s * dw.x);
        float sn, cs; sincosf((float)s * dw.y, &sn, &cs);
        acc += cp[2 * n] * (ew * cs) - cp[2 * n + 1] * (ew * sn);
    }
    ws[OFF_K + (size_t)lh * 64 + s] = 2.0f * acc;
}

// ---------------------------------------------------------------------------
// P0d: Toeplitz frag table TKF[s][tau] = (tau>=s) ? k[tau-s] : 0  (parallel)
// ---------------------------------------------------------------------------
__global__ __launch_bounds__(256) void prep_tkf(float* ws) {
    int idx = blockIdx.x * 256 + threadIdx.x;        // lh*4096 + s*64 + tau
    int tau = idx & 63;
    int s   = (idx >> 6) & 63;
    int lh  = idx >> 12;
    float v = (tau >= s) ? ws[OFF_K + (size_t)lh * 64 + (tau - s)] : 0.0f;
    unsigned short* dst = (unsigned short*)(ws + OFF_TKF) + (size_t)lh * 8192;
    store_hl(dst, (s >> 3) * 1024 + (s & 7) + tau * 16, v);
}

// ---------------------------------------------------------------------------
// P0e: conv_w -> bf16
// ---------------------------------------------------------------------------
__global__ __launch_bounds__(256) void prep_wbf(const float* conv_w, float* ws) {
    int i = blockIdx.x * 256 + threadIdx.x;
    ((unsigned short*)(ws + OFF_WB))[i] = f2bf(conv_w[i]);
}

// ---------------------------------------------------------------------------
// Encoder -> u bf16
// ---------------------------------------------------------------------------
__global__ __launch_bounds__(256) void encoder_kernel(const float* x, const float* enc_w,
                                                      const float* enc_b, float* ws) {
    __shared__ float wlds[H_ * DIN];
    __shared__ float blds[H_];
    int t  = threadIdx.x;
    int b  = blockIdx.x >> 4;
    int l0 = (blockIdx.x & 15) * 256;
    for (int i = t; i < H_ * DIN; i += 256) wlds[i] = enc_w[i];
    if (t < H_) blds[t] = enc_b[t];
    float xr[16];
    const float* xp = x + ((size_t)b * L_ + l0 + t) * DIN;
    #pragma unroll
    for (int d = 0; d < 16; ++d) xr[d] = xp[d];
    __syncthreads();
    unsigned short* u = (unsigned short*)(ws + OFF_U) + (size_t)b * H_ * L_ + l0 + t;
    for (int h = 0; h < H_; ++h) {
        float acc = blds[h];
        #pragma unroll
        for (int d = 0; d < 16; ++d) acc += xr[d] * wlds[h * 16 + d];
        u[(size_t)h * L_] = f2bf(acc);
    }
}

// ---------------------------------------------------------------------------
// S4D via bf16 MFMA (T tables hi/lo corrected; z/G pure bf16).
// One block per (b,h). Parallel 3-level cross-chunk scan (round-10 verbatim).
// ---------------------------------------------------------------------------
__global__ __launch_bounds__(256) void s4d_mfma(const float* Dp, float* ws, int layer) {
    __shared__ unsigned short zsh[64 * ZP];   // z, then G (bf16)
    __shared__ float eg[64 * EP];             // E (f32)
    __shared__ float tex[8][64];              // octave totals (complex packed)
    __shared__ float bex[8][64];              // exclusive octave bases

    int t  = threadIdx.x;
    int b  = blockIdx.x >> 7;
    int h  = blockIdx.x & 127;
    int lh = layer * H_ + h;
    int w  = t >> 6;
    int l  = t & 63;
    int lr = l & 15;
    int lg = l >> 4;

    const unsigned short* ug = (const unsigned short*)(ws + OFF_U) + ((size_t)b * H_ + h) * L_;

    // stage z: straight bf16 copy (16 elements per thread)
    {
        int base = t * 16;
        int c = base >> 6, s0 = base & 63;
        *(u16x8*)&zsh[c * ZP + s0]     = *(const u16x8*)&ug[base];
        *(u16x8*)&zsh[c * ZP + s0 + 8] = *(const u16x8*)&ug[base + 8];
    }

    // preload B-frags (global, L2-hot): T1F + TKF, kblk 0/1
    const unsigned short* t1f = (const unsigned short*)(ws + OFF_T1F) + (size_t)lh * 8192;
    const unsigned short* tkf = (const unsigned short*)(ws + OFF_TKF) + (size_t)lh * 8192;
    const unsigned short* t2f = (const unsigned short*)(ws + OFF_T2F) + (size_t)lh * 8192;
    int bo = lg * 1024 + (w * 16 + lr) * 16;
    bf16x8 T1h0 = BCB(*(const u16x8*)&t1f[bo]);
    bf16x8 T1l0 = BCB(*(const u16x8*)&t1f[bo + 8]);
    bf16x8 T1h1 = BCB(*(const u16x8*)&t1f[bo + 4096]);
    bf16x8 T1l1 = BCB(*(const u16x8*)&t1f[bo + 4096 + 8]);
    bf16x8 TKh0 = BCB(*(const u16x8*)&tkf[bo]);
    bf16x8 TKl0 = BCB(*(const u16x8*)&tkf[bo + 8]);
    bf16x8 TKh1 = BCB(*(const u16x8*)&tkf[bo + 4096]);
    bf16x8 TKl1 = BCB(*(const u16x8*)&tkf[bo + 4096 + 8]);

    f32x4 accE[4], accC[4];
    #pragma unroll
    for (int ct = 0; ct < 4; ++ct) { accE[ct] = (f32x4)0.0f; accC[ct] = (f32x4)0.0f; }

    __syncthreads();

    // ---- Pass A: E = z x (T1h+T1l) ; Yconv = z x (TKh+TKl)
    #pragma unroll
    for (int ct = 0; ct < 4; ++ct) {
        int ar = (ct * 16 + lr) * ZP;
        bf16x8 ah0 = BCB(*(const u16x8*)&zsh[ar + lg * 8]);
        bf16x8 ah1 = BCB(*(const u16x8*)&zsh[ar + 32 + lg * 8]);
        accE[ct] = MFMA(ah0, T1h0, accE[ct]);
        accE[ct] = MFMA(ah0, T1l0, accE[ct]);
        accE[ct] = MFMA(ah1, T1h1, accE[ct]);
        accE[ct] = MFMA(ah1, T1l1, accE[ct]);
        accC[ct] = MFMA(ah0, TKh0, accC[ct]);
        accC[ct] = MFMA(ah0, TKl0, accC[ct]);
        accC[ct] = MFMA(ah1, TKh1, accC[ct]);
        accC[ct] = MFMA(ah1, TKl1, accC[ct]);
    }
    // write E (D-frag: row=(lg*4+r), col=lr)
    #pragma unroll
    for (int ct = 0; ct < 4; ++ct)
        #pragma unroll
        for (int r = 0; r < 4; ++r)
            eg[(ct * 16 + lg * 4 + r) * EP + w * 16 + lr] = accE[ct][r];

    // preload T2F frags; pre-extract epilogue z (zsh reused for G after)
    bf16x8 T2h0 = BCB(*(const u16x8*)&t2f[bo]);
    bf16x8 T2l0 = BCB(*(const u16x8*)&t2f[bo + 8]);
    bf16x8 T2h1 = BCB(*(const u16x8*)&t2f[bo + 4096]);
    bf16x8 T2l1 = BCB(*(const u16x8*)&t2f[bo + 4096 + 8]);
    float zep[16];
    #pragma unroll
    for (int ct = 0; ct < 4; ++ct)
        #pragma unroll
        for (int r = 0; r < 4; ++r) {
            int c = ct * 16 + lg * 4 + r, tau = w * 16 + lr;
            zep[ct * 4 + r] = bf2f(zsh[c * ZP + tau]);
        }
    __syncthreads();

    // ---- Parallel scan: thread = (n = t&31, oct = t>>5); 8 chunks each
    {
        int n   = t & 31;
        int oct = t >> 5;
        const float* cp   = ws + OFF_CP  + (size_t)lh * 64;
        const float* w64p = ws + OFF_W64 + (size_t)lh * 64;
        const float* w5p  = ws + OFF_W5  + (size_t)lh * 64;
        float cre = cp[2 * n], cim = cp[2 * n + 1];
        float wr  = w64p[2 * n], wi = w64p[2 * n + 1];
        float2 e[8];
        float sre = 0.f, sim = 0.f;
        #pragma unroll
        for (int j = 0; j < 8; ++j) {                 // local octave scan
            e[j] = *(const float2*)&eg[(8 * oct + j) * EP + 2 * n];
            float nr = fmaf(wr, sre, fmaf(-wi, sim, e[j].x));
            float ni = fmaf(wr, sim, fmaf(wi, sre, e[j].y));
            sre = nr; sim = ni;
        }
        *(float2*)&tex[oct][2 * n] = make_float2(sre, sim);
        __syncthreads();
        if (t < 32) {                                 // exclusive base scan over octaves
            float Wr = w5p[2 * n], Wi = w5p[2 * n + 1];
            float br = 0.f, bi = 0.f;
            #pragma unroll
            for (int o = 0; o < 8; ++o) {
                *(float2*)&bex[o][2 * n] = make_float2(br, bi);
                float2 T = *(const float2*)&tex[o][2 * n];
                float nr = fmaf(Wr, br, fmaf(-Wi, bi, T.x));
                float ni = fmaf(Wr, bi, fmaf(Wi, br, T.y));
                br = nr; bi = ni;
            }
        }
        __syncthreads();
        float2 Sb = *(const float2*)&bex[oct][2 * n];
        sre = Sb.x; sim = Sb.y;
        #pragma unroll
        for (int j = 0; j < 8; ++j) {                 // replay: emit G bf16 (packed u32)
            int c = 8 * oct + j;
            float gre = 2.0f * (cre * sre - cim * sim);
            float gim = -2.0f * (cre * sim + cim * sre);
            unsigned int pk = (unsigned int)f2bf(gre) | ((unsigned int)f2bf(gim) << 16);
            *(unsigned int*)&zsh[c * ZP + 2 * n] = pk;
            float nr = fmaf(wr, sre, fmaf(-wi, sim, e[j].x));
            float ni = fmaf(wr, sim, fmaf(wi, sre, e[j].y));
            sre = nr; sim = ni;
        }
    }
    float Dh = Dp[lh];
    __syncthreads();

    // ---- Pass B: Y += G x (T2h+T2l)
    #pragma unroll
    for (int ct = 0; ct < 4; ++ct) {
        int ar = (ct * 16 + lr) * ZP;
        bf16x8 gh0 = BCB(*(const u16x8*)&zsh[ar + lg * 8]);
        bf16x8 gh1 = BCB(*(const u16x8*)&zsh[ar + 32 + lg * 8]);
        accC[ct] = MFMA(gh0, T2h0, accC[ct]);
        accC[ct] = MFMA(gh0, T2l0, accC[ct]);
        accC[ct] = MFMA(gh1, T2h1, accC[ct]);
        accC[ct] = MFMA(gh1, T2l1, accC[ct]);
    }

    // ---- epilogue: + D*z, tanh-GELU, store y bf16 (block-exclusive row)
    unsigned short* yb = (unsigned short*)(ws + OFF_Y) + ((size_t)b * H_ + h) * L_;
    #pragma unroll
    for (int ct = 0; ct < 4; ++ct)
        #pragma unroll
        for (int r = 0; r < 4; ++r) {
            float acc = fmaf(Dh, zep[ct * 4 + r], accC[ct][r]);
            yb[(ct * 16 + lg * 4 + r) * 64 + w * 16 + lr] = f2bf(gelu_f(acc));
        }
}

// ---------------------------------------------------------------------------
// Channel mix via bf16 MFMA + GLU + residual(bf16) + LN -> u bf16.
// R12 structure verbatim (no launch_bounds beyond block size).
// If last!=0, also write emb output f32 [b][l][h] from registers.
// ---------------------------------------------------------------------------
__global__ __launch_bounds__(256) void conv_glu_ln_mfma(const float* conv_b, const float* ln_w,
                                                        const float* ln_b, float* ws, float* outp,
                                                        int layer, int last) {
    __shared__ unsigned short yt[64 * 128];   // [l][h], swizzled
    __shared__ float wsum[4][64];
    __shared__ float wsq[4][64];

    int t    = threadIdx.x;
    int b    = blockIdx.x >> 6;
    int l0   = (blockIdx.x & 63) * 64;
    int w    = t >> 6;
    int lam  = t & 63;
    int g4   = lam >> 4;
    int ncol = lam & 15;

    const unsigned short* yg = (const unsigned short*)(ws + OFF_Y) + (size_t)b * H_ * L_;
    const unsigned short* wb = (const unsigned short*)(ws + OFF_WB) + (size_t)layer * 256 * 128;

    // ---- stage y transposed: column loads (coalesced across lanes), b128 writes
    {
        int ll = t & 63;
        int hb = (t >> 6) * 32;
        const unsigned short* ycol = yg + l0 + ll;
        #pragma unroll
        for (int g = 0; g < 4; ++g) {
            u16x8 tmp;
            #pragma unroll
            for (int i = 0; i < 8; ++i)
                tmp[i] = ycol[(size_t)(hb + g * 8 + i) * L_];
            *(u16x8*)&yt[yswz(ll, hb + g * 8)] = tmp;
        }
    }

    // ---- bias init
    const float* cb = conv_b + layer * 256;
    f32x4 dA[2][4], dG[2][4];
    #pragma unroll
    for (int oa = 0; oa < 2; ++oa) {
        int ba = w * 32 + oa * 16 + g4 * 4;
        f32x4 bA, bG;
        #pragma unroll
        for (int r = 0; r < 4; ++r) { bA[r] = cb[ba + r]; bG[r] = cb[128 + ba + r]; }
        #pragma unroll
        for (int nt = 0; nt < 4; ++nt) { dA[oa][nt] = bA; dG[oa][nt] = bG; }
    }
    __syncthreads();

    // ---- K loop: per kt, A-frags from global (L2), B-frags via b128 LDS reads
    #pragma unroll
    for (int kt = 0; kt < 4; ++kt) {
        bf16x8 aAk[2], aGk[2];
        #pragma unroll
        for (int oa = 0; oa < 2; ++oa) {
            int oA = w * 32 + oa * 16 + ncol;
            aAk[oa] = BCB(*(const u16x8*)&wb[(size_t)oA * 128 + kt * 32 + g4 * 8]);
            aGk[oa] = BCB(*(const u16x8*)&wb[(size_t)(128 + oA) * 128 + kt * 32 + g4 * 8]);
        }
        #pragma unroll
        for (int nt = 0; nt < 4; ++nt) {
            bf16x8 bfr = BCB(*(const u16x8*)&yt[yswz(nt * 16 + ncol, kt * 32 + g4 * 8)]);
            #pragma unroll
            for (int oa = 0; oa < 2; ++oa) {
                dA[oa][nt] = MFMA(aAk[oa], bfr, dA[oa][nt]);
                dG[oa][nt] = MFMA(aGk[oa], bfr, dG[oa][nt]);
            }
        }
    }

    // ---- epilogue: GLU + residual (bf16); LN over 128 channels
    unsigned short* ug = (unsigned short*)(ws + OFF_U) + (size_t)b * H_ * L_;
    float lwv[2][4], lbv[2][4];
    #pragma unroll
    for (int oa = 0; oa < 2; ++oa)
        #pragma unroll
        for (int r = 0; r < 4; ++r) {
            int hh = layer * 128 + w * 32 + oa * 16 + g4 * 4 + r;
            lwv[oa][r] = ln_w[hh]; lbv[oa][r] = ln_b[hh];
        }

    #pragma unroll
    for (int nt = 0; nt < 4; ++nt) {
        int l = l0 + nt * 16 + ncol;
        float s = 0.f, q = 0.f;
        #pragma unroll
        for (int oa = 0; oa < 2; ++oa)
            #pragma unroll
            for (int r = 0; r < 4; ++r) {
                int h = w * 32 + oa * 16 + g4 * 4 + r;
                float a = dA[oa][nt][r], g = dG[oa][nt][r];
                float val = a / (1.0f + __expf(-g)) + bf2f(ug[(size_t)h * L_ + l]);
                dA[oa][nt][r] = val;
                s += val; q += val * val;
            }
        s += __shfl_xor(s, 16, 64); q += __shfl_xor(q, 16, 64);
        s += __shfl_xor(s, 32, 64); q += __shfl_xor(q, 32, 64);
        if (g4 == 0) { wsum[w][nt * 16 + ncol] = s; wsq[w][nt * 16 + ncol] = q; }
    }
    __syncthreads();

    #pragma unroll
    for (int nt = 0; nt < 4; ++nt) {
        int ll = nt * 16 + ncol;
        int l  = l0 + ll;
        float S = wsum[0][ll] + wsum[1][ll] + wsum[2][ll] + wsum[3][ll];
        float Q = wsq[0][ll] + wsq[1][ll] + wsq[2][ll] + wsq[3][ll];
        float mu = S * (1.0f / 128.0f);
        float var = Q * (1.0f / 128.0f) - mu * mu;
        float rstd = rsqrtf(var + 1e-5f);
        #pragma unroll
        for (int oa = 0; oa < 2; ++oa) {
            float vv[4];
            #pragma unroll
            for (int r = 0; r < 4; ++r) {
                int h = w * 32 + oa * 16 + g4 * 4 + r;
                float v = (dA[oa][nt][r] - mu) * rstd * lwv[oa][r] + lbv[oa][r];
                vv[r] = v;
                ug[(size_t)h * L_ + l] = f2bf(v);
            }
            if (last) {
                *(float4*)&outp[((size_t)(b * L_ + l)) * H_ + w * 32 + oa * 16 + g4 * 4] =
                    make_float4(vv[0], vv[1], vv[2], vv[3]);
            }
        }
    }
}

// ---------------------------------------------------------------------------
// Mean-pool over L per (b,h)
// ---------------------------------------------------------------------------
__global__ __launch_bounds__(256) void pool_kernel(float* ws) {
    int bh = blockIdx.x;
    const unsigned short* u = (const unsigned short*)(ws + OFF_U) + (size_t)bh * L_;
    int t = threadIdx.x;
    float s = 0.0f;
    for (int i = t; i < L_; i += 256) s += bf2f(u[i]);
    #pragma unroll
    for (int m = 1; m <= 32; m <<= 1) s += __shfl_xor(s, m, 64);
    __shared__ float part[4];
    if ((t & 63) == 0) part[t >> 6] = s;
    __syncthreads();
    if (t == 0) ws[OFF_PL + bh] = (part[0] + part[1] + part[2] + part[3]) * (1.0f / L_);
}

// ---------------------------------------------------------------------------
// Decoder (f32 out)
// ---------------------------------------------------------------------------
__global__ __launch_bounds__(256) void decode_kernel(const float* dec_w, const float* dec_b,
                                                     const float* ws, float* out) {
    int t = threadIdx.x;
    int b = t >> 3, o = t & 7;
    const float* p = ws + OFF_PL + b * 128;
    float acc = dec_b[o];
    for (int h = 0; h < 128; ++h) acc += p[h] * dec_w[o * 128 + h];
    out[t] = 1.0f / (1.0f + __expf(-acc));
}

// ---------------------------------------------------------------------------
extern "C" void kernel_launch(void* const* d_in, const int* in_sizes, int n_in,
                              void* d_out, int out_size, void* d_ws, size_t ws_size,
                              hipStream_t stream) {
    const float* x          = (const float*)d_in[0];
    const float* enc_w      = (const float*)d_in[2];
    const float* enc_b      = (const float*)d_in[3];
    const float* log_dt     = (const float*)d_in[4];
    const float* log_A_real = (const float*)d_in[5];
    const float* A_imag     = (const float*)d_in[6];
    const float* C_re       = (const float*)d_in[7];
    const float* C_im       = (const float*)d_in[8];
    const float* Dp         = (const float*)d_in[9];
    const float* conv_w     = (const float*)d_in[10];
    const float* conv_b     = (const float*)d_in[11];
    const float* ln_w       = (const float*)d_in[12];
    const float* ln_b       = (const float*)d_in[13];
    const float* dec_w      = (const float*)d_in[14];
    const float* dec_b      = (const float*)d_in[15];
    float* ws = (float*)d_ws;
    float* out = (float*)d_out;

    prep_params<<<(NL_ * H_ * N2_ + 255) / 256, 256, 0, stream>>>(log_dt, log_A_real, A_imag,
                                                                  C_re, C_im, ws);
    prep_pow<<<(NL_ * H_ * N2_ * 64) / 256, 256, 0, stream>>>(ws);
    compute_k<<<(NL_ * H_ * 64 + 255) / 256, 256, 0, stream>>>(ws);
    prep_tkf<<<(NL_ * H_ * 64 * 64) / 256, 256, 0, stream>>>(ws);
    prep_wbf<<<(NL_ * 256 * 128) / 256, 256, 0, stream>>>(conv_w, ws);
    encoder_kernel<<<B_ * (L_ / 256), 256, 0, stream>>>(x, enc_w, enc_b, ws);
    for (int l = 0; l < NL_; ++l) {
        s4d_mfma<<<B_ * H_, 256, 0, stream>>>(Dp, ws, l);
        conv_glu_ln_mfma<<<B_ * (L_ / 64), 256, 0, stream>>>(conv_b, ln_w, ln_b, ws,
                                                             out + 256, l, l == NL_ - 1);
    }
    pool_kernel<<<B_ * H_, 256, 0, stream>>>(ws);
    decode_kernel<<<1, 256, 0, stream>>>(dec_w, dec_b, ws, out);
}